// Round 3
// baseline (232.948 us; speedup 1.0000x reference)
//
#include <hip/hip_runtime.h>
#include <hip/hip_bf16.h>

#define N 8192
#define D 1024
#define MARGIN 1.0f
#define EPS 1e-6f

typedef __attribute__((ext_vector_type(8))) short bf16x8;
typedef __attribute__((ext_vector_type(4))) float f32x4;
typedef __attribute__((ext_vector_type(8))) _Float16 f16x8;
typedef __attribute__((ext_vector_type(4))) _Float16 f16x4;
typedef __attribute__((ext_vector_type(8))) unsigned short u16x8;

__device__ inline unsigned short f2bf(float x) {
    unsigned u = __float_as_uint(x);
    unsigned r = (u + 0x7FFFu + ((u >> 16) & 1u)) >> 16;  // RNE
    return (unsigned short)r;
}

__device__ inline float h2f(unsigned hb) {
    return (float)__builtin_bit_cast(_Float16, (unsigned short)hb);
}

// Kernel 0: fp32 -> bf16 copy + per-row sum of squares + cls fold-in.
__global__ __launch_bounds__(256) void prep_kernel(const float* __restrict__ E,
                                                   const int* __restrict__ target,
                                                   unsigned short* __restrict__ Ebf,
                                                   float* __restrict__ sq,
                                                   unsigned char* __restrict__ cls) {
    const int r = blockIdx.x;
    const int tid = threadIdx.x;
    const float4 v = ((const float4*)(E + (size_t)r * D))[tid];
    ushort4 o;
    o.x = f2bf(v.x); o.y = f2bf(v.y); o.z = f2bf(v.z); o.w = f2bf(v.w);
    ((ushort4*)(Ebf + (size_t)r * D))[tid] = o;
    float s = v.x * v.x + v.y * v.y + v.z * v.z + v.w * v.w;
    for (int off = 32; off > 0; off >>= 1) s += __shfl_down(s, off);
    __shared__ float red[4];
    const int lane = tid & 63, wave = tid >> 6;
    if (lane == 0) red[wave] = s;
    __syncthreads();
    if (tid == 0) {
        sq[r] = red[0] + red[1] + red[2] + red[3];
        cls[r] = (unsigned char)target[r];
    }
}

// ---------------------------------------------------------------------------
// Kernel 1 (merged): ids 0..495 = strict-lower 256^2 tiles, 8-phase schedule
// (2 clean rounds at 1 block/CU). ids 496..591 = 96 diagonal 128^2 sub-tiles
// (light blocks, ~5us each) -- dispatched LAST so they fill the 16-CU slack in
// round 2 (496 = 248*2): diagonal work hides entirely in the round structure.
// ---------------------------------------------------------------------------

#define SLOT_0A0 0
#define SLOT_0A1 16384
#define SLOT_0B0 32768
#define SLOT_0B1 49152
#define SLOT_1A0 65536
#define SLOT_1A1 81920
#define SLOT_1B0 98304
#define SLOT_1B1 114688

// Stage one 16 KB half-tile (256 rows x 32 bf16) = 2 global_load_lds x 16B/lane.
// LDS dest is linear; the chunk swizzle is applied on the GLOBAL source address.
#define STAGE(slotOff, baseRow, kcol) do {                                              \
    const unsigned short* _s0 = E + (size_t)((baseRow) + (tid >> 2)) * D + (kcol) + stc * 8; \
    __builtin_amdgcn_global_load_lds(                                                    \
        (const __attribute__((address_space(1))) unsigned int*)_s0,                      \
        (__attribute__((address_space(3))) unsigned int*)(smem + (slotOff) + wave * 1024), 16, 0, 0); \
    const unsigned short* _s1 = _s0 + (size_t)128 * D;                                   \
    __builtin_amdgcn_global_load_lds(                                                    \
        (const __attribute__((address_space(1))) unsigned int*)_s1,                      \
        (__attribute__((address_space(3))) unsigned int*)(smem + (slotOff) + 8192 + wave * 1024), 16, 0, 0); \
} while (0)

// One phase: ds-read subtile | stage next half-tile | setprio(1) 16 MFMA
// setprio(0) | [vmcnt(6)] | single barrier.
#define PHASE(b, ks, mq, LOADB, SLOT_ST, TILE_ST, BASE_ST, KH_ST, DO_VM) do {            \
    const char* _As = smem + (b) * 65536 + (ks) * 16384;                                 \
    const char* _Bs = smem + (b) * 65536 + 32768 + (ks) * 16384;                         \
    if (LOADB) {                                                                         \
        _Pragma("unroll") for (int nj = 0; nj < 4; ++nj)                                 \
            bfr[nj] = *(const bf16x8*)(_Bs + (wn * 64 + nj * 16 + mr) * 64 + swz);       \
    }                                                                                    \
    bf16x8 af[4];                                                                        \
    _Pragma("unroll") for (int mi = 0; mi < 4; ++mi)                                     \
        af[mi] = *(const bf16x8*)(_As + (wm * 128 + (mq) * 64 + mi * 16 + mr) * 64 + swz); \
    STAGE(SLOT_ST, BASE_ST, (TILE_ST) * 64 + (KH_ST));                                   \
    __builtin_amdgcn_s_setprio(1);                                                       \
    _Pragma("unroll") for (int mi = 0; mi < 4; ++mi)                                     \
        _Pragma("unroll") for (int nj = 0; nj < 4; ++nj)                                 \
            acc[(mq) * 4 + mi][nj] = __builtin_amdgcn_mfma_f32_16x16x32_bf16(            \
                af[mi], bfr[nj], acc[(mq) * 4 + mi][nj], 0, 0, 0);                       \
    __builtin_amdgcn_s_setprio(0);                                                       \
    if (DO_VM) __asm__ __volatile__("s_waitcnt vmcnt(6)" ::: "memory");                  \
    __asm__ __volatile__("s_barrier" ::: "memory");                                      \
} while (0)

// Light path: one 128^2 diagonal sub-tile, 512 threads / 8 waves (each 64x32),
// 4-slot LDS ring (32 KB/slot: A 16KB + B 16KB), stage 2 tiles ahead,
// counted vmcnt(4), single barrier per K-step.
__device__ __forceinline__ void diag_path(char* smem,
                                          const unsigned short* __restrict__ E,
                                          const float* __restrict__ sq,
                                          _Float16* __restrict__ D2h,
                                          const int c, const int tid) {
    const int lane = tid & 63;
    const int wave = tid >> 6;           // 0..7
    const int wmL = wave >> 2;           // 0..1 : 64-row half
    const int wnL = wave & 3;            // 0..3 : 32-col quarter
    const int mr = lane & 15;
    const int q = lane >> 4;
    const int kq = q * 8;

    const int t = c / 3, s = c - 3 * t;
    const int smi = (s + 1) >> 1;        // 0,1,1
    const int sni = s >> 1;              // 0,0,1
    const int rm = t * 256 + smi * 128;
    const int cn = t * 256 + sni * 128;
    const bool offdiag = (s == 1);

    f32x4 acc[4][2] = {};

#define DSTAGE(sl, kk) do {                                                              \
    __builtin_amdgcn_global_load_lds(                                                    \
        (const __attribute__((address_space(1))) unsigned int*)(E + (size_t)(rm + (tid >> 2)) * D + (kk) * 32 + (tid & 3) * 8), \
        (__attribute__((address_space(3))) unsigned int*)(smem + (sl) * 32768 + wave * 1024), 16, 0, 0); \
    __builtin_amdgcn_global_load_lds(                                                    \
        (const __attribute__((address_space(1))) unsigned int*)(E + (size_t)(cn + (tid >> 2)) * D + (kk) * 32 + (tid & 3) * 8), \
        (__attribute__((address_space(3))) unsigned int*)(smem + (sl) * 32768 + 16384 + wave * 1024), 16, 0, 0); \
} while (0)

    DSTAGE(0, 0);
    DSTAGE(1, 1);
    for (int k = 0; k < 32; ++k) {
        const int kn = (k + 2 < 32) ? k + 2 : 31;   // restage last tile (uniform vmcnt)
        DSTAGE((k + 2) & 3, kn);
        __asm__ __volatile__("s_waitcnt vmcnt(4)" ::: "memory");
        __asm__ __volatile__("s_barrier" ::: "memory");
        const unsigned short* As = (const unsigned short*)(smem + (size_t)(k & 3) * 32768);
        const unsigned short* Bs = As + 8192;
        bf16x8 af[4], bfv[2];
#pragma unroll
        for (int mi = 0; mi < 4; ++mi)
            af[mi] = *(const bf16x8*)(As + (wmL * 64 + mi * 16 + mr) * 32 + kq);
#pragma unroll
        for (int ni = 0; ni < 2; ++ni)
            bfv[ni] = *(const bf16x8*)(Bs + (wnL * 32 + ni * 16 + mr) * 32 + kq);
#pragma unroll
        for (int mi = 0; mi < 4; ++mi)
#pragma unroll
            for (int ni = 0; ni < 2; ++ni)
                acc[mi][ni] = __builtin_amdgcn_mfma_f32_16x16x32_bf16(af[mi], bfv[ni], acc[mi][ni], 0, 0, 0);
    }
#undef DSTAGE
    __syncthreads();   // drains dangling restage DMA before smem reuse as Ts

    _Float16* Ts = (_Float16*)smem;      // 128 x (stride 136) fp16
    float sqjL[2];
#pragma unroll
    for (int ni = 0; ni < 2; ++ni) sqjL[ni] = sq[cn + wnL * 32 + ni * 16 + mr];
#pragma unroll
    for (int mi = 0; mi < 4; ++mi) {
        const int lrow = wmL * 64 + mi * 16 + q * 4;
        const int i0 = rm + lrow;
        const f32x4 sqi = *(const f32x4*)(sq + i0);
#pragma unroll
        for (int ni = 0; ni < 2; ++ni) {
            const int lcol = wnL * 32 + ni * 16 + mr;
            const int j = cn + lcol;
            f16x4 tv;
#pragma unroll
            for (int r = 0; r < 4; ++r) {
                const float d2 = fmaxf(sqi[r] + sqjL[ni] - 2.0f * acc[mi][ni][r], 0.0f);
                const _Float16 h = (_Float16)d2;
                D2h[(size_t)(i0 + r) * N + j] = h;
                tv[r] = h;
            }
            if (offdiag)
                *(f16x4*)(Ts + (size_t)lcol * 136 + lrow) = tv;
        }
    }
    if (offdiag) {
        __syncthreads();
#pragma unroll
        for (int it = 0; it < 4; ++it) {
            const int rt = it * 32 + (tid >> 4);
            const int seg = tid & 15;
            f16x8 v = *(const f16x8*)(Ts + (size_t)rt * 136 + seg * 8);
            *(f16x8*)(D2h + (size_t)(cn + rt) * N + rm + seg * 8) = v;
        }
    }
}

__global__ __launch_bounds__(512, 2) void gemm_kernel(const unsigned short* __restrict__ E,
                                                      const float* __restrict__ sq,
                                                      _Float16* __restrict__ D2h) {
    extern __shared__ char smem[];

    const int tid = threadIdx.x;            // 0..511

    if (blockIdx.x >= 496) {                // light diagonal blocks, dispatched last
        diag_path(smem, E, sq, D2h, blockIdx.x - 496, tid);
        return;
    }

    const int lane = tid & 63;
    const int wave = tid >> 6;              // 0..7
    const int wm = wave >> 2;               // M-half (128 rows)
    const int wn = wave & 3;                // N-quarter (64 cols)
    const int mr = lane & 15;
    const int q = lane >> 4;
    const int swz = ((q ^ ((mr >> 1) & 3)) << 4);   // ds_read chunk swizzle
    const int stc = (tid & 3) ^ ((tid >> 3) & 3);   // stage source chunk (inverse swz)

    // XCD swizzle (496 % 8 == 0): XCD x processes contiguous tile range.
    const int h = blockIdx.x;
    const int l = (h & 7) * 62 + (h >> 3);

    // strict-lower decode: by*(by-1)/2 <= l < by*(by+1)/2, bx < by
    int by = (int)((1.0f + sqrtf(8.0f * (float)l + 1.0f)) * 0.5f);
    while (by * (by - 1) / 2 > l) --by;
    while ((by + 1) * by / 2 <= l) ++by;
    const int bx = l - by * (by - 1) / 2;
    const int rm = by * 256;
    const int cn = bx * 256;

    f32x4 acc[8][4] = {};
    bf16x8 bfr[4];

    // Prologue: stage 5 half-tiles (T0 complete + T1.A0), wait oldest 2 done.
    STAGE(SLOT_0A0, rm, 0);
    STAGE(SLOT_0B0, cn, 0);
    STAGE(SLOT_0A1, rm, 32);
    STAGE(SLOT_0B1, cn, 32);
    STAGE(SLOT_1A0, rm, 64);
    __asm__ __volatile__("s_waitcnt vmcnt(6)" ::: "memory");
    __asm__ __volatile__("s_barrier" ::: "memory");

    for (int i = 0; i < 8; ++i) {
        const int kt = 2 * i;
        const int t2 = (kt + 2 < 16) ? kt + 2 : 15;   // clamp: restage tile 15
        const int t3 = (kt + 3 < 16) ? kt + 3 : 15;   // (keeps vmcnt accounting
                                                      //  uniform)
        PHASE(0, 0, 0, 1, SLOT_1B0, kt + 1, cn, 0, 0);
        PHASE(0, 0, 1, 0, SLOT_1A1, kt + 1, rm, 32, 1);
        PHASE(0, 1, 0, 1, SLOT_1B1, kt + 1, cn, 32, 0);
        PHASE(0, 1, 1, 0, SLOT_0A0, t2, rm, 0, 1);
        PHASE(1, 0, 0, 1, SLOT_0B0, t2, cn, 0, 0);
        PHASE(1, 0, 1, 0, SLOT_0A1, t2, rm, 32, 1);
        PHASE(1, 1, 0, 1, SLOT_0B1, t2, cn, 32, 0);
        PHASE(1, 1, 1, 0, SLOT_1A0, t3, rm, 0, 1);
    }

    // Drain dangling restage DMA before reusing smem as the transpose buffer.
    __asm__ __volatile__("s_waitcnt vmcnt(0) lgkmcnt(0)" ::: "memory");
    __asm__ __volatile__("s_barrier" ::: "memory");

    // Epilogue: D2 = max(sq_i + sq_j - 2*acc, 0) -> fp16.
    // Direct tile: scalar stores (L2 write-combines row runs).
    // Mirror tile: stash transposed in smem (256x256 fp16 = 128 KB exactly,
    // 16B-chunk XOR swizzle c^=(j&31) breaks the 512B-row bank degeneracy),
    // then stream out fully-coalesced 16B row stores.
    const int crow = q * 4;
    float sqj[4];
#pragma unroll
    for (int nj = 0; nj < 4; ++nj) sqj[nj] = sq[cn + wn * 64 + nj * 16 + mr];
#pragma unroll
    for (int mg = 0; mg < 8; ++mg) {
        const int iloc = wm * 128 + mg * 16 + crow;
        const int i0 = rm + iloc;
        const f32x4 sqi = *(const f32x4*)(sq + i0);
        const unsigned cch = (unsigned)iloc >> 3;         // 16B chunk in row
        const unsigned cof = ((unsigned)iloc & 7) << 1;   // byte offset in chunk
#pragma unroll
        for (int nj = 0; nj < 4; ++nj) {
            const int jloc = wn * 64 + nj * 16 + mr;
            const int j = cn + jloc;
            f16x4 tv;
#pragma unroll
            for (int r = 0; r < 4; ++r) {
                const float d2 = fmaxf(sqi[r] + sqj[nj] - 2.0f * acc[mg][nj][r], 0.0f);
                const _Float16 h16 = (_Float16)d2;
                tv[r] = h16;
                D2h[(size_t)(i0 + r) * N + j] = h16;
            }
            *(f16x4*)(smem + (size_t)jloc * 512 + ((cch ^ (jloc & 31)) << 4) + cof) = tv;
        }
    }
    __syncthreads();
    {
        const int jr = tid >> 1;           // 0..255: row of the mirror tile
        const int hf = tid & 1;            // which 128-col half
        _Float16* dst = D2h + (size_t)(cn + jr) * N + rm + hf * 128;
#pragma unroll
        for (int st = 0; st < 16; ++st) {
            const unsigned cc = (unsigned)(hf * 16 + st);
            f16x8 v = *(const f16x8*)(smem + (size_t)jr * 512 + ((cc ^ (jr & 31)) << 4));
            *(f16x8*)(dst + st * 8) = v;
        }
    }
}

// Kernel 2: one BLOCK per anchor row, single global pass, value-only mining.
// Non-negative fp16 orders as u16 bits, so all reductions are u32 max/min on
// raw half-bits. Pass 2 runs from a 16-VGPR register stash (32 elems/thread).
// Loss from fp16 d2 values directly (index-free; EPS effect ~1e-6, negligible).
__global__ __launch_bounds__(256) void mine_kernel(const _Float16* __restrict__ D2h,
                                                   const unsigned char* __restrict__ cls,
                                                   float* __restrict__ loss_arr) {
    const int i = blockIdx.x;
    const int tid = threadIdx.x;
    const int lane = tid & 63, wave = tid >> 6;
    const unsigned tcb = cls[i];
    const unsigned short* row = (const unsigned short*)(D2h + (size_t)i * N);

    u16x8 v[4];
    unsigned long long c8[4];
#pragma unroll
    for (int it = 0; it < 4; ++it) {
        v[it] = *(const u16x8*)(row + it * 2048 + tid * 8);
        c8[it] = *(const unsigned long long*)(cls + it * 2048 + tid * 8);
    }

    // Pass 1: pm = max same-class bits (self ~0, never max); nm = min diff-class bits.
    unsigned pm = 0u, nm = 0xFFFFu;
#pragma unroll
    for (int it = 0; it < 4; ++it) {
#pragma unroll
        for (int e = 0; e < 8; ++e) {
            const unsigned hb = v[it][e];
            const bool s = ((unsigned)(c8[it] >> (8 * e)) & 0xFFu) == tcb;
            pm = max(pm, s ? hb : 0u);
            nm = min(nm, s ? 0xFFFFu : hb);
        }
    }
    for (int off = 1; off < 64; off <<= 1) {
        pm = max(pm, (unsigned)__shfl_xor((int)pm, off));
        nm = min(nm, (unsigned)__shfl_xor((int)nm, off));
    }
    __shared__ unsigned redp[4], redn[4], reds[4];
    if (lane == 0) { redp[wave] = pm; redn[wave] = nm; }
    __syncthreads();
    pm = max(max(redp[0], redp[1]), max(redp[2], redp[3]));
    nm = min(min(redn[0], redn[1]), min(redn[2], redn[3]));
    const unsigned lob = pm;

    // Pass 2 (register stash): sm = min bits strictly above lob.
    // Strict > excludes all positives (<= lob) and self. No class test needed.
    unsigned sm = 0xFFFFu;
#pragma unroll
    for (int it = 0; it < 4; ++it) {
#pragma unroll
        for (int e = 0; e < 8; ++e) {
            const unsigned hb = v[it][e];
            sm = min(sm, hb > lob ? hb : 0xFFFFu);
        }
    }
    for (int off = 1; off < 64; off <<= 1)
        sm = min(sm, (unsigned)__shfl_xor((int)sm, off));
    if (lane == 0) reds[wave] = sm;
    __syncthreads();
    if (tid == 0) {
        sm = min(min(reds[0], reds[1]), min(reds[2], reds[3]));
        const float lo = h2f(lob);
        const float dp = sqrtf(lo);
        const float hw = dp + MARGIN;
        const float hi = hw * hw;
        const float smv = h2f(sm);                   // 0xFFFF -> NaN -> fallback
        const float dn2 = (smv < hi) ? smv : h2f(nm);
        loss_arr[i] = fmaxf(dp - sqrtf(dn2) + MARGIN, 0.0f);
    }
}

// Kernel 3: mean over 8192 per-anchor losses.
__global__ __launch_bounds__(256) void reduce_kernel(const float* __restrict__ loss_arr,
                                                     float* __restrict__ out) {
    const int tid = threadIdx.x;
    float s = 0.0f;
    for (int k = tid; k < N; k += 256) s += loss_arr[k];
    for (int off = 32; off > 0; off >>= 1) s += __shfl_down(s, off);
    __shared__ float red[4];
    const int lane = tid & 63, wave = tid >> 6;
    if (lane == 0) red[wave] = s;
    __syncthreads();
    if (tid == 0) out[0] = (red[0] + red[1] + red[2] + red[3]) * (1.0f / N);
}

extern "C" void kernel_launch(void* const* d_in, const int* in_sizes, int n_in,
                              void* d_out, int out_size, void* d_ws, size_t ws_size,
                              hipStream_t stream) {
    const float* E = (const float*)d_in[0];
    const int* target = (const int*)d_in[1];
    float* out = (float*)d_out;
    char* ws = (char*)d_ws;

    // Workspace layout (~144.1 MB):
    unsigned short* Ebf = (unsigned short*)ws;                            // 16 MB
    float* sq        = (float*)(ws + (size_t)16777216);                   // 32 KB
    float* loss_arr  = (float*)(ws + (size_t)16809984);                   // 32 KB
    unsigned char* cls = (unsigned char*)(ws + (size_t)16842752);         // 8 KB (padded 32 KB)
    _Float16* D2h    = (_Float16*)(ws + (size_t)16875520);                // 128 MB

    static bool attr_set = false;
    if (!attr_set) {
        hipFuncSetAttribute((const void*)gemm_kernel,
                            hipFuncAttributeMaxDynamicSharedMemorySize, 131072);
        attr_set = true;
    }

    prep_kernel<<<N, 256, 0, stream>>>(E, target, Ebf, sq, cls);
    gemm_kernel<<<592, 512, 131072, stream>>>(Ebf, sq, D2h);  // 496 lower-tri + 96 diag-light
    mine_kernel<<<N, 256, 0, stream>>>(D2h, cls, loss_arr);
    reduce_kernel<<<1, 256, 0, stream>>>(loss_arr, out);
}

// Round 4
// 185.441 us; speedup vs baseline: 1.2562x; 1.2562x over previous
//
#include <hip/hip_runtime.h>
#include <hip/hip_bf16.h>

#define N 8192
#define D 1024
#define MARGIN 1.0f
#define EPS 1e-6f

typedef __attribute__((ext_vector_type(8))) short bf16x8;
typedef __attribute__((ext_vector_type(4))) float f32x4;
typedef __attribute__((ext_vector_type(8))) _Float16 f16x8;
typedef __attribute__((ext_vector_type(4))) _Float16 f16x4;
typedef __attribute__((ext_vector_type(8))) unsigned short u16x8;

__device__ inline unsigned short f2bf(float x) {
    unsigned u = __float_as_uint(x);
    unsigned r = (u + 0x7FFFu + ((u >> 16) & 1u)) >> 16;  // RNE
    return (unsigned short)r;
}

__device__ inline float h2f(unsigned hb) {
    return (float)__builtin_bit_cast(_Float16, (unsigned short)hb);
}

// Kernel 0: fp32 -> bf16 copy + per-row sum of squares + cls fold-in.
__global__ __launch_bounds__(256) void prep_kernel(const float* __restrict__ E,
                                                   const int* __restrict__ target,
                                                   unsigned short* __restrict__ Ebf,
                                                   float* __restrict__ sq,
                                                   unsigned char* __restrict__ cls) {
    const int r = blockIdx.x;
    const int tid = threadIdx.x;
    const float4 v = ((const float4*)(E + (size_t)r * D))[tid];
    ushort4 o;
    o.x = f2bf(v.x); o.y = f2bf(v.y); o.z = f2bf(v.z); o.w = f2bf(v.w);
    ((ushort4*)(Ebf + (size_t)r * D))[tid] = o;
    float s = v.x * v.x + v.y * v.y + v.z * v.z + v.w * v.w;
    for (int off = 32; off > 0; off >>= 1) s += __shfl_down(s, off);
    __shared__ float red[4];
    const int lane = tid & 63, wave = tid >> 6;
    if (lane == 0) red[wave] = s;
    __syncthreads();
    if (tid == 0) {
        sq[r] = red[0] + red[1] + red[2] + red[3];
        cls[r] = (unsigned char)target[r];
    }
}

// ---------------------------------------------------------------------------
// Kernel 1 (merged): ids 0..495 = strict-lower 256^2 tiles, 8-phase schedule
// (2 clean rounds at 1 block/CU). ids 496..591 = 96 diagonal 128^2 sub-tiles
// (light blocks) dispatched last, filling round-2/3 scheduling slack.
// ---------------------------------------------------------------------------

#define SLOT_0A0 0
#define SLOT_0A1 16384
#define SLOT_0B0 32768
#define SLOT_0B1 49152
#define SLOT_1A0 65536
#define SLOT_1A1 81920
#define SLOT_1B0 98304
#define SLOT_1B1 114688

// Stage one 16 KB half-tile (256 rows x 32 bf16) = 2 global_load_lds x 16B/lane.
// LDS dest is linear; the chunk swizzle is applied on the GLOBAL source address.
#define STAGE(slotOff, baseRow, kcol) do {                                              \
    const unsigned short* _s0 = E + (size_t)((baseRow) + (tid >> 2)) * D + (kcol) + stc * 8; \
    __builtin_amdgcn_global_load_lds(                                                    \
        (const __attribute__((address_space(1))) unsigned int*)_s0,                      \
        (__attribute__((address_space(3))) unsigned int*)(smem + (slotOff) + wave * 1024), 16, 0, 0); \
    const unsigned short* _s1 = _s0 + (size_t)128 * D;                                   \
    __builtin_amdgcn_global_load_lds(                                                    \
        (const __attribute__((address_space(1))) unsigned int*)_s1,                      \
        (__attribute__((address_space(3))) unsigned int*)(smem + (slotOff) + 8192 + wave * 1024), 16, 0, 0); \
} while (0)

// One phase: ds-read subtile | stage next half-tile | setprio(1) 16 MFMA
// setprio(0) | [vmcnt(6)] | single barrier.
#define PHASE(b, ks, mq, LOADB, SLOT_ST, TILE_ST, BASE_ST, KH_ST, DO_VM) do {            \
    const char* _As = smem + (b) * 65536 + (ks) * 16384;                                 \
    const char* _Bs = smem + (b) * 65536 + 32768 + (ks) * 16384;                         \
    if (LOADB) {                                                                         \
        _Pragma("unroll") for (int nj = 0; nj < 4; ++nj)                                 \
            bfr[nj] = *(const bf16x8*)(_Bs + (wn * 64 + nj * 16 + mr) * 64 + swz);       \
    }                                                                                    \
    bf16x8 af[4];                                                                        \
    _Pragma("unroll") for (int mi = 0; mi < 4; ++mi)                                     \
        af[mi] = *(const bf16x8*)(_As + (wm * 128 + (mq) * 64 + mi * 16 + mr) * 64 + swz); \
    STAGE(SLOT_ST, BASE_ST, (TILE_ST) * 64 + (KH_ST));                                   \
    __builtin_amdgcn_s_setprio(1);                                                       \
    _Pragma("unroll") for (int mi = 0; mi < 4; ++mi)                                     \
        _Pragma("unroll") for (int nj = 0; nj < 4; ++nj)                                 \
            acc[(mq) * 4 + mi][nj] = __builtin_amdgcn_mfma_f32_16x16x32_bf16(            \
                af[mi], bfr[nj], acc[(mq) * 4 + mi][nj], 0, 0, 0);                       \
    __builtin_amdgcn_s_setprio(0);                                                       \
    if (DO_VM) __asm__ __volatile__("s_waitcnt vmcnt(6)" ::: "memory");                  \
    __asm__ __volatile__("s_barrier" ::: "memory");                                      \
} while (0)

// Light path: one 128^2 diagonal sub-tile, 512 threads / 8 waves (each 64x32),
// 4-slot LDS ring (32 KB/slot: A 16KB + B 16KB), stage 2 tiles ahead,
// counted vmcnt(4), single barrier per K-step.
__device__ __forceinline__ void diag_path(char* smem,
                                          const unsigned short* __restrict__ E,
                                          const float* __restrict__ sq,
                                          _Float16* __restrict__ D2h,
                                          const int c, const int tid) {
    const int lane = tid & 63;
    const int wave = tid >> 6;           // 0..7
    const int wmL = wave >> 2;           // 0..1 : 64-row half
    const int wnL = wave & 3;            // 0..3 : 32-col quarter
    const int mr = lane & 15;
    const int q = lane >> 4;
    const int kq = q * 8;

    const int t = c / 3, s = c - 3 * t;
    const int smi = (s + 1) >> 1;        // 0,1,1
    const int sni = s >> 1;              // 0,0,1
    const int rm = t * 256 + smi * 128;
    const int cn = t * 256 + sni * 128;
    const bool offdiag = (s == 1);

    f32x4 acc[4][2] = {};

#define DSTAGE(sl, kk) do {                                                              \
    __builtin_amdgcn_global_load_lds(                                                    \
        (const __attribute__((address_space(1))) unsigned int*)(E + (size_t)(rm + (tid >> 2)) * D + (kk) * 32 + (tid & 3) * 8), \
        (__attribute__((address_space(3))) unsigned int*)(smem + (sl) * 32768 + wave * 1024), 16, 0, 0); \
    __builtin_amdgcn_global_load_lds(                                                    \
        (const __attribute__((address_space(1))) unsigned int*)(E + (size_t)(cn + (tid >> 2)) * D + (kk) * 32 + (tid & 3) * 8), \
        (__attribute__((address_space(3))) unsigned int*)(smem + (sl) * 32768 + 16384 + wave * 1024), 16, 0, 0); \
} while (0)

    DSTAGE(0, 0);
    DSTAGE(1, 1);
    for (int k = 0; k < 32; ++k) {
        const int kn = (k + 2 < 32) ? k + 2 : 31;   // restage last tile (uniform vmcnt)
        DSTAGE((k + 2) & 3, kn);
        __asm__ __volatile__("s_waitcnt vmcnt(4)" ::: "memory");
        __asm__ __volatile__("s_barrier" ::: "memory");
        const unsigned short* As = (const unsigned short*)(smem + (size_t)(k & 3) * 32768);
        const unsigned short* Bs = As + 8192;
        bf16x8 af[4], bfv[2];
#pragma unroll
        for (int mi = 0; mi < 4; ++mi)
            af[mi] = *(const bf16x8*)(As + (wmL * 64 + mi * 16 + mr) * 32 + kq);
#pragma unroll
        for (int ni = 0; ni < 2; ++ni)
            bfv[ni] = *(const bf16x8*)(Bs + (wnL * 32 + ni * 16 + mr) * 32 + kq);
#pragma unroll
        for (int mi = 0; mi < 4; ++mi)
#pragma unroll
            for (int ni = 0; ni < 2; ++ni)
                acc[mi][ni] = __builtin_amdgcn_mfma_f32_16x16x32_bf16(af[mi], bfv[ni], acc[mi][ni], 0, 0, 0);
    }
#undef DSTAGE
    __syncthreads();   // drains dangling restage DMA before smem reuse as Ts

    _Float16* Ts = (_Float16*)smem;      // 128 x (stride 136) fp16
    float sqjL[2];
#pragma unroll
    for (int ni = 0; ni < 2; ++ni) sqjL[ni] = sq[cn + wnL * 32 + ni * 16 + mr];
#pragma unroll
    for (int mi = 0; mi < 4; ++mi) {
        const int lrow = wmL * 64 + mi * 16 + q * 4;
        const int i0 = rm + lrow;
        const f32x4 sqi = *(const f32x4*)(sq + i0);
#pragma unroll
        for (int ni = 0; ni < 2; ++ni) {
            const int lcol = wnL * 32 + ni * 16 + mr;
            const int j = cn + lcol;
            f16x4 tv;
#pragma unroll
            for (int r = 0; r < 4; ++r) {
                const float d2 = fmaxf(sqi[r] + sqjL[ni] - 2.0f * acc[mi][ni][r], 0.0f);
                const _Float16 h = (_Float16)d2;
                D2h[(size_t)(i0 + r) * N + j] = h;
                tv[r] = h;
            }
            if (offdiag)
                *(f16x4*)(Ts + (size_t)lcol * 136 + lrow) = tv;
        }
    }
    if (offdiag) {
        __syncthreads();
#pragma unroll
        for (int it = 0; it < 4; ++it) {
            const int rt = it * 32 + (tid >> 4);
            const int seg = tid & 15;
            f16x8 v = *(const f16x8*)(Ts + (size_t)rt * 136 + seg * 8);
            *(f16x8*)(D2h + (size_t)(cn + rt) * N + rm + seg * 8) = v;
        }
    }
}

__global__ __launch_bounds__(512, 2) void gemm_kernel(const unsigned short* __restrict__ E,
                                                      const float* __restrict__ sq,
                                                      _Float16* __restrict__ D2h) {
    extern __shared__ char smem[];

    const int tid = threadIdx.x;            // 0..511

    if (blockIdx.x >= 496) {                // light diagonal blocks, dispatched last
        diag_path(smem, E, sq, D2h, blockIdx.x - 496, tid);
        return;
    }

    const int lane = tid & 63;
    const int wave = tid >> 6;              // 0..7
    const int wm = wave >> 2;               // M-half (128 rows)
    const int wn = wave & 3;                // N-quarter (64 cols)
    const int mr = lane & 15;
    const int q = lane >> 4;
    const int swz = ((q ^ ((mr >> 1) & 3)) << 4);   // ds_read chunk swizzle
    const int stc = (tid & 3) ^ ((tid >> 3) & 3);   // stage source chunk (inverse swz)

    // XCD swizzle (496 % 8 == 0): XCD x processes contiguous tile range.
    const int h = blockIdx.x;
    const int l = (h & 7) * 62 + (h >> 3);

    // strict-lower decode: by*(by-1)/2 <= l < by*(by+1)/2, bx < by
    int by = (int)((1.0f + sqrtf(8.0f * (float)l + 1.0f)) * 0.5f);
    while (by * (by - 1) / 2 > l) --by;
    while ((by + 1) * by / 2 <= l) ++by;
    const int bx = l - by * (by - 1) / 2;
    const int rm = by * 256;
    const int cn = bx * 256;

    f32x4 acc[8][4] = {};
    bf16x8 bfr[4];

    // Prologue: stage 5 half-tiles (T0 complete + T1.A0), wait oldest 2 done.
    STAGE(SLOT_0A0, rm, 0);
    STAGE(SLOT_0B0, cn, 0);
    STAGE(SLOT_0A1, rm, 32);
    STAGE(SLOT_0B1, cn, 32);
    STAGE(SLOT_1A0, rm, 64);
    __asm__ __volatile__("s_waitcnt vmcnt(6)" ::: "memory");
    __asm__ __volatile__("s_barrier" ::: "memory");

    for (int i = 0; i < 8; ++i) {
        const int kt = 2 * i;
        const int t2 = (kt + 2 < 16) ? kt + 2 : 15;   // clamp: restage tile 15
        const int t3 = (kt + 3 < 16) ? kt + 3 : 15;   // (keeps vmcnt accounting
                                                      //  uniform)
        PHASE(0, 0, 0, 1, SLOT_1B0, kt + 1, cn, 0, 0);
        PHASE(0, 0, 1, 0, SLOT_1A1, kt + 1, rm, 32, 1);
        PHASE(0, 1, 0, 1, SLOT_1B1, kt + 1, cn, 32, 0);
        PHASE(0, 1, 1, 0, SLOT_0A0, t2, rm, 0, 1);
        PHASE(1, 0, 0, 1, SLOT_0B0, t2, cn, 0, 0);
        PHASE(1, 0, 1, 0, SLOT_0A1, t2, cn == rm ? cn : rm, 32, 1);
        PHASE(1, 1, 0, 1, SLOT_0B1, t2, cn, 32, 0);
        PHASE(1, 1, 1, 0, SLOT_1A0, t3, rm, 0, 1);
    }

    // Drain dangling restage DMA before reusing smem as the transpose buffer.
    __asm__ __volatile__("s_waitcnt vmcnt(0) lgkmcnt(0)" ::: "memory");
    __asm__ __volatile__("s_barrier" ::: "memory");

    // Epilogue: D2 = max(sq_i + sq_j - 2*acc, 0) -> fp16.
    // Direct tile: scalar stores (16 consecutive lanes = 32B row runs; clean
    // in R0/R2). Mirror tile: stash transposed in smem (256x256 fp16 = 128 KB,
    // 16B-chunk XOR swizzle c^=(j&31) breaks the 512B-row bank degeneracy),
    // then stream out with LANE-CONTIGUOUS rows: each half-wave writes one
    // full 512B row (R3's one-row-per-lane scatter caused +90MB HBM write).
    const int crow = q * 4;
    float sqj[4];
#pragma unroll
    for (int nj = 0; nj < 4; ++nj) sqj[nj] = sq[cn + wn * 64 + nj * 16 + mr];
#pragma unroll
    for (int mg = 0; mg < 8; ++mg) {
        const int iloc = wm * 128 + mg * 16 + crow;
        const int i0 = rm + iloc;
        const f32x4 sqi = *(const f32x4*)(sq + i0);
        const unsigned cch = (unsigned)iloc >> 3;         // 16B chunk in row
        const unsigned cof = ((unsigned)iloc & 7) << 1;   // byte offset in chunk
#pragma unroll
        for (int nj = 0; nj < 4; ++nj) {
            const int jloc = wn * 64 + nj * 16 + mr;
            const int j = cn + jloc;
            f16x4 tv;
#pragma unroll
            for (int r = 0; r < 4; ++r) {
                const float d2 = fmaxf(sqi[r] + sqj[nj] - 2.0f * acc[mg][nj][r], 0.0f);
                const _Float16 h16 = (_Float16)d2;
                tv[r] = h16;
                D2h[(size_t)(i0 + r) * N + j] = h16;
            }
            *(f16x4*)(smem + (size_t)jloc * 512 + ((cch ^ (jloc & 31)) << 4) + cof) = tv;
        }
    }
    __syncthreads();
    {
        const int seg = tid & 31;          // 16B chunk within the row
#pragma unroll
        for (int it = 0; it < 16; ++it) {
            const int rt = it * 16 + (tid >> 5);   // mirror-tile row
            f16x8 v = *(const f16x8*)(smem + (size_t)rt * 512 + (((unsigned)seg ^ (rt & 31)) << 4));
            *(f16x8*)(D2h + (size_t)(cn + rt) * N + rm + seg * 8) = v;
        }
    }
}

// Kernel 2: one BLOCK per anchor row, single global pass, value-only mining.
// Non-negative fp16 orders as u16 bits, so all reductions are u32 max/min on
// raw half-bits. Pass 2 runs from a 16-VGPR register stash (32 elems/thread).
// Loss from fp16 d2 values directly (index-free; EPS effect ~1e-6, negligible).
__global__ __launch_bounds__(256) void mine_kernel(const _Float16* __restrict__ D2h,
                                                   const unsigned char* __restrict__ cls,
                                                   float* __restrict__ loss_arr) {
    const int i = blockIdx.x;
    const int tid = threadIdx.x;
    const int lane = tid & 63, wave = tid >> 6;
    const unsigned tcb = cls[i];
    const unsigned short* row = (const unsigned short*)(D2h + (size_t)i * N);

    u16x8 v[4];
    unsigned long long c8[4];
#pragma unroll
    for (int it = 0; it < 4; ++it) {
        v[it] = *(const u16x8*)(row + it * 2048 + tid * 8);
        c8[it] = *(const unsigned long long*)(cls + it * 2048 + tid * 8);
    }

    // Pass 1: pm = max same-class bits (self ~0, never max); nm = min diff-class bits.
    unsigned pm = 0u, nm = 0xFFFFu;
#pragma unroll
    for (int it = 0; it < 4; ++it) {
#pragma unroll
        for (int e = 0; e < 8; ++e) {
            const unsigned hb = v[it][e];
            const bool s = ((unsigned)(c8[it] >> (8 * e)) & 0xFFu) == tcb;
            pm = max(pm, s ? hb : 0u);
            nm = min(nm, s ? 0xFFFFu : hb);
        }
    }
    for (int off = 1; off < 64; off <<= 1) {
        pm = max(pm, (unsigned)__shfl_xor((int)pm, off));
        nm = min(nm, (unsigned)__shfl_xor((int)nm, off));
    }
    __shared__ unsigned redp[4], redn[4], reds[4];
    if (lane == 0) { redp[wave] = pm; redn[wave] = nm; }
    __syncthreads();
    pm = max(max(redp[0], redp[1]), max(redp[2], redp[3]));
    nm = min(min(redn[0], redn[1]), min(redn[2], redn[3]));
    const unsigned lob = pm;

    // Pass 2 (register stash): sm = min bits strictly above lob.
    // Strict > excludes all positives (<= lob) and self. No class test needed.
    unsigned sm = 0xFFFFu;
#pragma unroll
    for (int it = 0; it < 4; ++it) {
#pragma unroll
        for (int e = 0; e < 8; ++e) {
            const unsigned hb = v[it][e];
            sm = min(sm, hb > lob ? hb : 0xFFFFu);
        }
    }
    for (int off = 1; off < 64; off <<= 1)
        sm = min(sm, (unsigned)__shfl_xor((int)sm, off));
    if (lane == 0) reds[wave] = sm;
    __syncthreads();
    if (tid == 0) {
        sm = min(min(reds[0], reds[1]), min(reds[2], reds[3]));
        const float lo = h2f(lob);
        const float dp = sqrtf(lo);
        const float hw = dp + MARGIN;
        const float hi = hw * hw;
        const float smv = h2f(sm);                   // 0xFFFF -> NaN -> fallback
        const float dn2 = (smv < hi) ? smv : h2f(nm);
        loss_arr[i] = fmaxf(dp - sqrtf(dn2) + MARGIN, 0.0f);
    }
}

// Kernel 3: mean over 8192 per-anchor losses.
__global__ __launch_bounds__(256) void reduce_kernel(const float* __restrict__ loss_arr,
                                                     float* __restrict__ out) {
    const int tid = threadIdx.x;
    float s = 0.0f;
    for (int k = tid; k < N; k += 256) s += loss_arr[k];
    for (int off = 32; off > 0; off >>= 1) s += __shfl_down(s, off);
    __shared__ float red[4];
    const int lane = tid & 63, wave = tid >> 6;
    if (lane == 0) red[wave] = s;
    __syncthreads();
    if (tid == 0) out[0] = (red[0] + red[1] + red[2] + red[3]) * (1.0f / N);
}

extern "C" void kernel_launch(void* const* d_in, const int* in_sizes, int n_in,
                              void* d_out, int out_size, void* d_ws, size_t ws_size,
                              hipStream_t stream) {
    const float* E = (const float*)d_in[0];
    const int* target = (const int*)d_in[1];
    float* out = (float*)d_out;
    char* ws = (char*)d_ws;

    // Workspace layout (~144.1 MB):
    unsigned short* Ebf = (unsigned short*)ws;                            // 16 MB
    float* sq        = (float*)(ws + (size_t)16777216);                   // 32 KB
    float* loss_arr  = (float*)(ws + (size_t)16809984);                   // 32 KB
    unsigned char* cls = (unsigned char*)(ws + (size_t)16842752);         // 8 KB (padded 32 KB)
    _Float16* D2h    = (_Float16*)(ws + (size_t)16875520);                // 128 MB

    static bool attr_set = false;
    if (!attr_set) {
        hipFuncSetAttribute((const void*)gemm_kernel,
                            hipFuncAttributeMaxDynamicSharedMemorySize, 131072);
        attr_set = true;
    }

    prep_kernel<<<N, 256, 0, stream>>>(E, target, Ebf, sq, cls);
    gemm_kernel<<<592, 512, 131072, stream>>>(Ebf, sq, D2h);  // 496 lower-tri + 96 diag-light
    mine_kernel<<<N, 256, 0, stream>>>(D2h, cls, loss_arr);
    reduce_kernel<<<1, 256, 0, stream>>>(loss_arr, out);
}